// Round 4
// baseline (2177.887 us; speedup 1.0000x reference)
//
#include <hip/hip_runtime.h>
#include <math.h>

typedef _Float16 f16;
typedef _Float16 f16x8 __attribute__((ext_vector_type(8)));
typedef float    f32x4 __attribute__((ext_vector_type(4)));

#define MFMA16(A, B, C) __builtin_amdgcn_mfma_f32_16x16x32_f16((A), (B), (C), 0, 0, 0)
#define LOG2E 1.44269504088896f

// sigma(z) = rcp(1 + 2^acc) with bare v_exp_f32; weights pre-scaled by
// -log2e (sigmoid gates) or -2*log2e (g gate), as in the proven round-0 math.
__device__ __forceinline__ float sig2(float a) {
    return __builtin_amdgcn_rcpf(1.0f + __builtin_amdgcn_exp2f(a));
}
__device__ __forceinline__ float tanh2(float c) {
    return fmaf(2.0f, sig2(c * (-2.0f * LOG2E)), -1.0f);
}

__device__ __forceinline__ f16x8 ldfrag(const float* __restrict__ W, int n, int k0, float s) {
    const float* p = W + (size_t)n * 64 + k0;
    f16x8 r;
#pragma unroll
    for (int j = 0; j < 8; j++) r[j] = (f16)(s * p[j]);
    return r;
}

// Slack-poll: consumer lags producer, so the flag is normally already
// satisfied (1 LDS read). Bounded spin: logic bug => wrong answer, not hang.
__device__ __forceinline__ void pollge(volatile unsigned* f, unsigned want) {
    int g = 0;
    while (*f < want) { if (++g > (1 << 23)) break; }
    asm volatile("" ::: "memory");
}

// ---------------------------------------------------------------------------
// Zero-barrier wave-specialized pipeline. One block per BATCH PAIR, 4 waves:
//   wave 0: encoder L1 (full cell in-wave; weights 128 VGPR + x-MFMA 64)
//   wave 1: encoder L2 (ih+hh = 256 weight VGPRs), consumes h1 ring w/ slack
//   wave 2: decoder dec1+dec2 fused in one wave (zero sync on the serial
//           c2->dec1->c1->dec2 chain; two in-wave LDS transposes per step)
//   wave 3: FC head, consumes h2d ring w/ slack, writes out rows
// MFMA layouts (16x16x32 f16, verified against round-0's working kernel):
//   A: lane l holds A[l&15][(l>>4)*8+j]  -> batch-replicated rows (c15&1)
//   B: lane l holds B[(l>>4)*8+j][l&15]  -> ldfrag
//   C: col=lane&15, row=(lane>>4)*4+reg  -> reg qb (qb=quad&1) = batch qb
// h buffers are stored transposed ([bat][unit] f16) so a ds_read_b128 at
// (c15&1)*64 + quad*8 (+32) IS the next A-frag: write->lgkmcnt(0)->read is
// the in-wave transpose.
// ---------------------------------------------------------------------------
__global__ __launch_bounds__(256, 1)
void seq2seq_kernel(const float* __restrict__ src, const float* __restrict__ trg,
                    const float* __restrict__ e1ih, const float* __restrict__ e1hh,
                    const float* __restrict__ e1b,
                    const float* __restrict__ e2ih, const float* __restrict__ e2hh,
                    const float* __restrict__ e2b,
                    const float* __restrict__ d1ih, const float* __restrict__ d1hh,
                    const float* __restrict__ d1b,
                    const float* __restrict__ d2ih, const float* __restrict__ d2hh,
                    const float* __restrict__ d2b,
                    const float* __restrict__ fcW, const float* __restrict__ fcb,
                    float* __restrict__ out)
{
    const int bp   = blockIdx.x;
    const int tid  = threadIdx.x;
    const int wv   = tid >> 6;               // 0..3
    const int lane = tid & 63;
    const int quad = lane >> 4;
    const int c15  = lane & 15;
    const int qb   = quad & 1;               // batch this lane extracts/acts on
    const int ab   = c15 & 1;                // batch this lane's A-row feeds

    __shared__ __align__(16) f16 xst[1024][8];    // src as f16, 16 KB
    __shared__ __align__(16) f16 tst[512][8];     // trg as f16, 8 KB
    __shared__ __align__(16) f16 h1r[16][2][64];  // L1 out ring [slot][bat][u], 4 KB
    __shared__ __align__(16) f16 h2b[2][64];      // L2 / dec h2 recurrent buffer
    __shared__ __align__(16) f16 h1d[2][64];      // dec1 -> dec2 in-wave transpose
    __shared__ float c2buf[2][64];                // L2 final c2 -> dec
    __shared__ __align__(16) f16 ring[2][32][72]; // h2d history for FC, 9 KB
    __shared__ unsigned flg[4];                   // 0=fL1 1=fL2 2=fDEC
    volatile unsigned* vflg = flg;

    // ---- one-time staging (f16) ----
    {
        const float* s0 = src + (size_t)(2 * bp) * 3072;
        const float* s1 = s0 + 3072;
        for (int i = tid; i < 3072; i += 256) {
            int t = i / 3, c = i - 3 * t;
            xst[t][c]     = (f16)s0[i];
            xst[t][4 + c] = (f16)s1[i];
        }
        const float* t0p = trg + (size_t)(2 * bp) * 1536;
        const float* t1p = t0p + 1536;
        for (int i = tid; i < 1536; i += 256) {
            int t = i / 3, c = i - 3 * t;
            tst[t][c]     = (f16)t0p[i];
            tst[t][4 + c] = (f16)t1p[i];
        }
    }
    { f16* z = &h1r[0][0][0]; for (int i = tid; i < 2048; i += 256) z[i] = (f16)0.f; }
    if (tid < 128) (&h2b[0][0])[tid] = (f16)0.f;
    if (tid < 4) flg[tid] = 0;
    __syncthreads();   // the only barrier in the kernel

    const f32x4 z4 = {0.f, 0.f, 0.f, 0.f};

    if (wv == 0) {
        // ================= encoder L1 =================
        f16x8 W0[16], W1f[16], XW[16];
#pragma unroll
        for (int t = 0; t < 16; t++) {
            const int g = t >> 2;
            const float s = (g == 2) ? (-2.0f * LOG2E) : (-LOG2E);
            const int n = g * 64 + (t & 3) * 16 + c15;
            W0[t]  = ldfrag(e1hh, n, quad * 8, s);
            W1f[t] = ldfrag(e1hh, n, 32 + quad * 8, s);
            f16x8 r = {};
            if (quad == 0) {
                r[0] = (f16)(s * e1ih[n * 3 + 0]);
                r[1] = (f16)(s * e1ih[n * 3 + 1]);
                r[2] = (f16)(s * e1ih[n * 3 + 2]);
                r[3] = (f16)(s * e1b[n]);
            }
            XW[t] = r;
        }
        float c1[4] = {0.f, 0.f, 0.f, 0.f};
#pragma unroll 1
        for (unsigned tau = 0; tau < 1024; ++tau) {
            f16x8 xa = {};
            {
                const f16* xp = &xst[tau][ab * 4];
                if (quad == 0) { xa[0] = xp[0]; xa[1] = xp[1]; xa[2] = xp[2]; xa[3] = (f16)1.0f; }
            }
            // ring back-pressure: writes tau..tau+7 overwrite ticks tau-16..tau-9,
            // consumed iff fL2 >= tau-8 (exact bound)
            if (tau >= 16 && (tau & 7) == 0) pollge(vflg + 1, tau - 8);
            f32x4 acc[16];
#pragma unroll
            for (int t = 0; t < 16; t++) acc[t] = MFMA16(xa, XW[t], z4);   // x+bias, K=4
            const f16* hb = &h1r[(tau + 15) & 15][0][0];                    // h1(tau-1)
            f16x8 a0 = *(const f16x8*)(hb + ab * 64 + quad * 8);
            f16x8 a1 = *(const f16x8*)(hb + ab * 64 + 32 + quad * 8);
#pragma unroll
            for (int t = 0; t < 16; t++)
                acc[t] = MFMA16(a1, W1f[t], MFMA16(a0, W0[t], acc[t]));
            float v[16];
#pragma unroll
            for (int t = 0; t < 16; t++) v[t] = qb ? acc[t][1] : acc[t][0];
            f16* hw = &h1r[tau & 15][0][0];
#pragma unroll
            for (int ut = 0; ut < 4; ut++) {
                float iv = sig2(v[ut]), fv = sig2(v[4 + ut]);
                float gv = fmaf(2.0f, sig2(v[8 + ut]), -1.0f), ov = sig2(v[12 + ut]);
                c1[ut] = fv * c1[ut] + iv * gv;
                if (quad < 2) hw[qb * 64 + ut * 16 + c15] = (f16)(ov * tanh2(c1[ut]));
            }
            asm volatile("s_waitcnt lgkmcnt(0)" ::: "memory");
            if (lane == 0) vflg[0] = tau + 1;
        }
    } else if (wv == 1) {
        // ================= encoder L2 =================
        f16x8 Wi0[16], Wi1[16], Wh0[16], Wh1[16];
        float b2v[16];
#pragma unroll
        for (int t = 0; t < 16; t++) {
            const int g = t >> 2;
            const float s = (g == 2) ? (-2.0f * LOG2E) : (-LOG2E);
            const int n = g * 64 + (t & 3) * 16 + c15;
            Wi0[t] = ldfrag(e2ih, n, quad * 8, s);
            Wi1[t] = ldfrag(e2ih, n, 32 + quad * 8, s);
            Wh0[t] = ldfrag(e2hh, n, quad * 8, s);
            Wh1[t] = ldfrag(e2hh, n, 32 + quad * 8, s);
            b2v[t] = s * e2b[n];
        }
        float c2r[4] = {0.f, 0.f, 0.f, 0.f};
#pragma unroll 1
        for (unsigned tau = 0; tau < 1024; ++tau) {
            if ((tau & 3) == 0) pollge(vflg + 0, tau + 4);   // slack-poll, 1/4 ticks
            const f16* hb = &h1r[tau & 15][0][0];            // h1(tau)
            f16x8 a0 = *(const f16x8*)(hb + ab * 64 + quad * 8);
            f16x8 a1 = *(const f16x8*)(hb + ab * 64 + 32 + quad * 8);
            const f16* pb = &h2b[0][0];                      // h2(tau-1), own write
            f16x8 b0 = *(const f16x8*)(pb + ab * 64 + quad * 8);
            f16x8 b1 = *(const f16x8*)(pb + ab * 64 + 32 + quad * 8);
            float v[16];
#pragma unroll
            for (int h = 0; h < 2; h++) {
                f32x4 acc[8];
#pragma unroll
                for (int tt = 0; tt < 8; tt++) {
                    const int t = h * 8 + tt;
                    acc[tt] = MFMA16(b1, Wh1[t], MFMA16(b0, Wh0[t],
                              MFMA16(a1, Wi1[t], MFMA16(a0, Wi0[t], z4))));
                }
#pragma unroll
                for (int tt = 0; tt < 8; tt++) {
                    const int t = h * 8 + tt;
                    v[t] = (qb ? acc[tt][1] : acc[tt][0]) + b2v[t];
                }
            }
            f16* hw = &h2b[0][0];
#pragma unroll
            for (int ut = 0; ut < 4; ut++) {
                float iv = sig2(v[ut]), fv = sig2(v[4 + ut]);
                float gv = fmaf(2.0f, sig2(v[8 + ut]), -1.0f), ov = sig2(v[12 + ut]);
                c2r[ut] = fv * c2r[ut] + iv * gv;
                if (quad < 2) hw[qb * 64 + ut * 16 + c15] = (f16)(ov * tanh2(c2r[ut]));
            }
            asm volatile("s_waitcnt lgkmcnt(0)" ::: "memory");
            if (lane == 0) vflg[1] = tau + 1;
        }
        // hand final c2 to the decoder wave (h2b already holds h2(1023))
#pragma unroll
        for (int ut = 0; ut < 4; ut++)
            if (quad < 2) c2buf[qb][ut * 16 + c15] = c2r[ut];
        asm volatile("s_waitcnt lgkmcnt(0)" ::: "memory");
        if (lane == 0) vflg[1] = 1026;   // ENC_DONE
    } else if (wv == 2) {
        // ================= decoder (dec1 + dec2 fused, zero sync) =========
        f16x8 D0[16], D1f[16], XW[16], S0[16], S1[16];
        float b2v[16];
#pragma unroll
        for (int t = 0; t < 16; t++) {
            const int g = t >> 2;
            const float s = (g == 2) ? (-2.0f * LOG2E) : (-LOG2E);
            const int n = g * 64 + (t & 3) * 16 + c15;
            D0[t]  = ldfrag(d1hh, n, quad * 8, s);
            D1f[t] = ldfrag(d1hh, n, 32 + quad * 8, s);
            {
                f16x8 r = {};
                if (quad == 0) {
                    r[0] = (f16)(s * d1ih[n * 3 + 0]);
                    r[1] = (f16)(s * d1ih[n * 3 + 1]);
                    r[2] = (f16)(s * d1ih[n * 3 + 2]);
                    r[3] = (f16)(s * d1b[n]);
                }
                XW[t] = r;
            }
            {
                const float* pa = d2ih + (size_t)n * 64 + quad * 8;
                const float* pc = d2hh + (size_t)n * 64 + quad * 8;
                f16x8 r;
#pragma unroll
                for (int j = 0; j < 8; j++) r[j] = (f16)(s * (pa[j] + pc[j]));
                S0[t] = r;
            }
            {
                const float* pa = d2ih + (size_t)n * 64 + 32 + quad * 8;
                const float* pc = d2hh + (size_t)n * 64 + 32 + quad * 8;
                f16x8 r;
#pragma unroll
                for (int j = 0; j < 8; j++) r[j] = (f16)(s * (pa[j] + pc[j]));
                S1[t] = r;
            }
            b2v[t] = s * d2b[n];
        }
        pollge(vflg + 1, 1026);              // wait for encoder final state
        float c2r[4];
#pragma unroll
        for (int ut = 0; ut < 4; ut++) c2r[ut] = c2buf[qb][ut * 16 + c15];
#pragma unroll 1
        for (unsigned t = 0; t < 511; ++t) {
            f16x8 xa = {};
            {
                const f16* xp = &tst[t][ab * 4];
                if (quad == 0) { xa[0] = xp[0]; xa[1] = xp[1]; xa[2] = xp[2]; xa[3] = (f16)1.0f; }
            }
            const f16* hb = &h2b[0][0];      // h2d(t-1)
            f16x8 a0 = *(const f16x8*)(hb + ab * 64 + quad * 8);
            f16x8 a1 = *(const f16x8*)(hb + ab * 64 + 32 + quad * 8);
            float v[16];
#pragma unroll
            for (int h = 0; h < 4; h++) {    // quarters: trims live acc regs
                f32x4 acc[4];
#pragma unroll
                for (int tt = 0; tt < 4; tt++) {
                    const int t2 = h * 4 + tt;
                    acc[tt] = MFMA16(a1, D1f[t2], MFMA16(a0, D0[t2], MFMA16(xa, XW[t2], z4)));
                }
#pragma unroll
                for (int tt = 0; tt < 4; tt++) {
                    const int t2 = h * 4 + tt;
                    v[t2] = qb ? acc[tt][1] : acc[tt][0];
                }
            }
            float c1d[4];
            f16* hw = &h1d[0][0];
#pragma unroll
            for (int ut = 0; ut < 4; ut++) {
                float iv = sig2(v[ut]), fv = sig2(v[4 + ut]);
                float gv = fmaf(2.0f, sig2(v[8 + ut]), -1.0f), ov = sig2(v[12 + ut]);
                c1d[ut] = fv * c2r[ut] + iv * gv;
                if (quad < 2) hw[qb * 64 + ut * 16 + c15] = (f16)(ov * tanh2(c1d[ut]));
            }
            asm volatile("s_waitcnt lgkmcnt(0)" ::: "memory");   // h1d committed
            const f16* np = &h1d[0][0];
            f16x8 m0 = *(const f16x8*)(np + ab * 64 + quad * 8);
            f16x8 m1 = *(const f16x8*)(np + ab * 64 + 32 + quad * 8);
#pragma unroll
            for (int h = 0; h < 4; h++) {
                f32x4 acc[4];
#pragma unroll
                for (int tt = 0; tt < 4; tt++) {
                    const int t2 = h * 4 + tt;
                    acc[tt] = MFMA16(m1, S1[t2], MFMA16(m0, S0[t2], z4));
                }
#pragma unroll
                for (int tt = 0; tt < 4; tt++) {
                    const int t2 = h * 4 + tt;
                    v[t2] = (qb ? acc[tt][1] : acc[tt][0]) + b2v[t2];
                }
            }
            f16* hw2 = &h2b[0][0];
            f16* rw  = &ring[0][0][0];
#pragma unroll
            for (int ut = 0; ut < 4; ut++) {
                float iv = sig2(v[ut]), fv = sig2(v[4 + ut]);
                float gv = fmaf(2.0f, sig2(v[8 + ut]), -1.0f), ov = sig2(v[12 + ut]);
                c2r[ut] = fv * c1d[ut] + iv * gv;
                if (quad < 2) {
                    f16 hh = (f16)(ov * tanh2(c2r[ut]));
                    hw2[qb * 64 + ut * 16 + c15] = hh;
                    rw[qb * 32 * 72 + (t & 31) * 72 + ut * 16 + c15] = hh;
                }
            }
            asm volatile("s_waitcnt lgkmcnt(0)" ::: "memory");
            if (lane == 0) vflg[2] = t + 1;
        }
    } else {
        // ================= FC head =================
        f16x8 FW0 = {}, FW1 = {};
        float fb = 0.f;
        if (c15 < 3) {
#pragma unroll
            for (int j = 0; j < 8; j++) {
                FW0[j] = (f16)fcW[c15 * 64 + quad * 8 + j];
                FW1[j] = (f16)fcW[c15 * 64 + 32 + quad * 8 + j];
            }
            fb = fcb[c15];
        }
#pragma unroll 1
        for (int k = 1; k <= 31; k++) {       // steps (k-1)*16 .. k*16-1 -> rows k*16-15..k*16
            pollge(vflg + 2, (unsigned)(k * 16));
            const int base = ((k - 1) * 16) & 31;
#pragma unroll
            for (int b = 0; b < 2; b++) {
                const f16* rp = &ring[b][0][0];
                f16x8 fa0 = *(const f16x8*)(rp + (base + c15) * 72 + quad * 8);
                f16x8 fa1 = *(const f16x8*)(rp + (base + c15) * 72 + 32 + quad * 8);
                f32x4 acc = MFMA16(fa1, FW1, MFMA16(fa0, FW0, z4));
                if (c15 < 3) {
                    float* ob = out + (((size_t)(2 * bp + b) * 512 + (k * 16 - 15)) * 3) + c15;
#pragma unroll
                    for (int rg = 0; rg < 4; rg++)
                        ob[(quad * 4 + rg) * 3] = acc[rg] + fb;
                }
            }
        }
        // drain: steps 496..510 (slots 16..30) -> rows 497..511
        pollge(vflg + 2, 511);
        {
            const int base = 16;
#pragma unroll
            for (int b = 0; b < 2; b++) {
                const f16* rp = &ring[b][0][0];
                f16x8 fa0 = *(const f16x8*)(rp + (base + c15) * 72 + quad * 8);
                f16x8 fa1 = *(const f16x8*)(rp + (base + c15) * 72 + 32 + quad * 8);
                f32x4 acc = MFMA16(fa1, FW1, MFMA16(fa0, FW0, z4));
                if (c15 < 3) {
                    float* ob = out + (((size_t)(2 * bp + b) * 512 + 497) * 3) + c15;
#pragma unroll
                    for (int rg = 0; rg < 4; rg++) {
                        int step = quad * 4 + rg;
                        if (step < 15) ob[step * 3] = acc[rg] + fb;
                    }
                }
            }
        }
    }
}

extern "C" void kernel_launch(void* const* d_in, const int* in_sizes, int n_in,
                              void* d_out, int out_size, void* d_ws, size_t ws_size,
                              hipStream_t stream)
{
    const float* src   = (const float*)d_in[0];
    const float* trg   = (const float*)d_in[1];
    const float* e1ih  = (const float*)d_in[2];
    const float* e1hh  = (const float*)d_in[3];
    const float* e1b   = (const float*)d_in[4];
    const float* e2ih  = (const float*)d_in[5];
    const float* e2hh  = (const float*)d_in[6];
    const float* e2b   = (const float*)d_in[7];
    const float* dd1ih = (const float*)d_in[8];
    const float* dd1hh = (const float*)d_in[9];
    const float* dd1b  = (const float*)d_in[10];
    const float* dd2ih = (const float*)d_in[11];
    const float* dd2hh = (const float*)d_in[12];
    const float* dd2b  = (const float*)d_in[13];
    const float* fcW   = (const float*)d_in[14];
    const float* fcb   = (const float*)d_in[15];
    float* out = (float*)d_out;

    // outputs[:, 0, :] stays 0; decoder fills t >= 1
    hipMemsetAsync(d_out, 0, (size_t)out_size * sizeof(float), stream);

    seq2seq_kernel<<<256, 256, 0, stream>>>(src, trg,
                                            e1ih, e1hh, e1b, e2ih, e2hh, e2b,
                                            dd1ih, dd1hh, dd1b, dd2ih, dd2hh, dd2b,
                                            fcW, fcb, out);
}

// Round 5
// 1965.458 us; speedup vs baseline: 1.1081x; 1.1081x over previous
//
#include <hip/hip_runtime.h>
#include <math.h>

typedef _Float16 f16;
typedef _Float16 f16x8 __attribute__((ext_vector_type(8)));
typedef float    f32x4 __attribute__((ext_vector_type(4)));

#define MFMA16(A, B, C) __builtin_amdgcn_mfma_f32_16x16x32_f16((A), (B), (C), 0, 0, 0)
#define LOG2E 1.44269504088896f

// sigma(z) = rcp(1 + 2^acc); weights pre-scaled by -log2e (sigmoid) or
// -2*log2e (g gate) -- same math as the proven round-0/round-4 kernels.
__device__ __forceinline__ float sig2(float a) {
    return __builtin_amdgcn_rcpf(1.0f + __builtin_amdgcn_exp2f(a));
}
__device__ __forceinline__ float tanh2(float c) {
    return fmaf(2.0f, sig2(c * (-2.0f * LOG2E)), -1.0f);
}
// frag t2 = q*4+g: gate g = t2&3 (i,f,g,o), unit group q = t2>>2
__device__ __forceinline__ int fragN(int t2, int c15) { return (t2 & 3) * 64 + (t2 >> 2) * 16 + c15; }
__device__ __forceinline__ float fragS(int t2) { return ((t2 & 3) == 2) ? (-2.0f * LOG2E) : (-LOG2E); }

__device__ __forceinline__ f16x8 ldfrag(const float* __restrict__ W, int n, int k0, float s) {
    const float* p = W + (size_t)n * 64 + k0;
    f16x8 r;
#pragma unroll
    for (int j = 0; j < 8; j++) r[j] = (f16)(s * p[j]);
    return r;
}

// Slack-poll: consumer normally trails producer, so the flag is already
// satisfied. Bounded spin: a protocol bug becomes a wrong answer, not a hang.
__device__ __forceinline__ void pollge(volatile unsigned* f, unsigned want) {
    unsigned g = 0;
    while (*f < want) { if (++g > (1u << 21)) break; }
    asm volatile("" ::: "memory");
}
__device__ __forceinline__ void pub(volatile unsigned* f, unsigned v, bool l0) {
    asm volatile("s_waitcnt lgkmcnt(0)" ::: "memory");
    if (l0) *f = v;
}

#define SMEM_BYTES 113184
#define FL1  0
#define FIP  1
#define FL2  2
#define FXP1 3
#define FXP  4
#define FDEC 5
#define FS   6

// ---------------------------------------------------------------------------
// Zero-barrier 4-wave pipeline, one block per BATCH PAIR (grid 256 = #CUs).
// All cross-wave links are slack-polled rings (flags normally pre-satisfied);
// the only recurrences are IN-WAVE (write LDS -> lgkmcnt(0) -> read back).
//  w0: enc L1 recurrence (e1hh in 128 VGPR; x-term from w3's xp ring)
//      -> then decoder x-projection producer (d1ih) into the same ring.
//  w1: enc L2 input projection (e2ih@h1+b, feed-forward, runs ahead) -> ipr
//      ring; also stages dec2 merged weights (d2ih+d2hh, f16 frags) + d2b
//      into LDS during early ticks.
//  w2: CRITICAL. enc L2 recurrence (e2hh only, 128 VGPR) -> fused decoder
//      dec1+dec2 (d1hh in regs; dec2 weights streamed from LDS in
//      double-buffered quarters). Keeps c2 state in registers across phases.
//  w3: enc L1 x-projection producer (e1ih) -> FC head (h2d ring, 2 MFMAs/16).
// MFMA maps (proven in rounds 0/4): A row=c15 (batch ab=c15&1 replicated),
// k=quad*8+j; B k rows, col=c15; C col=c15, row=quad*4+reg -> reg qb=quad&1.
// ---------------------------------------------------------------------------
__global__ __launch_bounds__(256, 1)
void seq2seq_kernel(const float* __restrict__ src, const float* __restrict__ trg,
                    const float* __restrict__ e1ih, const float* __restrict__ e1hh,
                    const float* __restrict__ e1b,
                    const float* __restrict__ e2ih, const float* __restrict__ e2hh,
                    const float* __restrict__ e2b,
                    const float* __restrict__ d1ih, const float* __restrict__ d1hh,
                    const float* __restrict__ d1b,
                    const float* __restrict__ d2ih, const float* __restrict__ d2hh,
                    const float* __restrict__ d2b,
                    const float* __restrict__ fcW, const float* __restrict__ fcb,
                    float* __restrict__ out)
{
    extern __shared__ __align__(16) char smem[];
    f16   (*h1r)[2][64]     = (f16 (*)[2][64])(smem);              // 16-slot h1 ring, 4 KB
    f16*    h2b             = (f16*)(smem + 4096);                 // [2][64] h2 recurrent
    f16*    h1d             = (f16*)(smem + 4352);                 // [2][64] dec1->dec2
    float (*ipr)[2][16][16] = (float (*)[2][16][16])(smem + 4608); // L2 input-proj ring, 32 KB
    float (*xpx)[2][16][16] = (float (*)[2][16][16])(smem + 37376);// x-proj ring (enc then dec), 32 KB
    f16   (*sfr)[64][8]     = (f16 (*)[64][8])(smem + 70144);      // dec2 weight frags, 32 KB
    float (*db2l)[16]       = (float (*)[16])(smem + 102912);      // dec2 bias, 1 KB
    f16   (*ringo)[32][72]  = (f16 (*)[32][72])(smem + 103936);    // h2d history for FC, 9 KB
    volatile unsigned* flg  = (volatile unsigned*)(smem + 113152);

    const int bp   = blockIdx.x;
    const int tid  = threadIdx.x;
    const int wv   = tid >> 6;
    const int lane = tid & 63;
    const int quad = lane >> 4;
    const int c15  = lane & 15;
    const int qb   = quad & 1;
    const int ab   = c15 & 1;
    const f32x4 z4 = {0.f, 0.f, 0.f, 0.f};

    { f16* z = &h1r[0][0][0];
      for (int i = tid; i < 2048; i += 256) z[i] = (f16)0.f; }
    if (tid < 128) h2b[tid] = (f16)0.f;
    if (tid < 8) ((volatile unsigned*)flg)[tid] = 0u;
    __syncthreads();   // the only barrier in the kernel

    if (wv == 0) {
        // ================= encoder L1 recurrence =================
        f16x8 W0[16], W1[16];
#pragma unroll
        for (int t2 = 0; t2 < 16; t2++) {
            const int n = fragN(t2, c15); const float s = fragS(t2);
            W0[t2] = ldfrag(e1hh, n, quad * 8, s);
            W1[t2] = ldfrag(e1hh, n, 32 + quad * 8, s);
        }
        float cs[4] = {0.f, 0.f, 0.f, 0.f};
        pollge(flg + FXP1, 5);
        f32x4 xt[4];
        { const float* xp = &xpx[0][qb][c15][0];
#pragma unroll
          for (int q = 0; q < 4; q++) xt[q] = *(const f32x4*)(xp + q * 4); }
#pragma unroll 1
        for (unsigned tau = 0; tau < 1024; ++tau) {
            if ((tau & 7) == 0 && tau >= 16) pollge(flg + FIP, tau - 8);
            if ((tau & 3) == 0) pollge(flg + FXP1, (tau + 5 > 1024u) ? 1024u : tau + 5);
            const f16* hb = &h1r[(tau + 15) & 15][0][0];
            f16x8 a0 = *(const f16x8*)(hb + ab * 64 + quad * 8);
            f16x8 a1 = *(const f16x8*)(hb + ab * 64 + 32 + quad * 8);
            f32x4 acc[16];
#pragma unroll
            for (int t2 = 0; t2 < 16; t2++)
                acc[t2] = MFMA16(a1, W1[t2], MFMA16(a0, W0[t2], z4));
            f16* hw = &h1r[tau & 15][0][0];
#pragma unroll
            for (int q = 0; q < 4; q++) {
                float v0 = (qb ? acc[q*4+0][1] : acc[q*4+0][0]) + xt[q][0];
                float v1 = (qb ? acc[q*4+1][1] : acc[q*4+1][0]) + xt[q][1];
                float v2 = (qb ? acc[q*4+2][1] : acc[q*4+2][0]) + xt[q][2];
                float v3 = (qb ? acc[q*4+3][1] : acc[q*4+3][0]) + xt[q][3];
                float iv = sig2(v0), fv = sig2(v1);
                float gv = fmaf(2.0f, sig2(v2), -1.0f), ov = sig2(v3);
                cs[q] = fv * cs[q] + iv * gv;
                if (quad < 2) hw[qb * 64 + q * 16 + c15] = (f16)(ov * tanh2(cs[q]));
            }
            pub(flg + FL1, tau + 1, lane == 0);
            { const float* xp = &xpx[(tau + 1) & 15][qb][c15][0];   // stale-safe at 1023
#pragma unroll
              for (int q = 0; q < 4; q++) xt[q] = *(const f32x4*)(xp + q * 4); }
        }
        // ================= decoder x-projection producer =================
        f16x8 XWd[16];
#pragma unroll
        for (int t2 = 0; t2 < 16; t2++) {
            const int n = fragN(t2, c15); const float s = fragS(t2);
            f16x8 r = {};
            if (quad == 0) {
                r[0] = (f16)(s * d1ih[n * 3 + 0]);
                r[1] = (f16)(s * d1ih[n * 3 + 1]);
                r[2] = (f16)(s * d1ih[n * 3 + 2]);
                r[3] = (f16)(s * d1b[n]);
            }
            XWd[t2] = r;
        }
#pragma unroll 1
        for (unsigned t = 0; t < 511; ++t) {
            if ((t & 7) == 0 && t >= 16) pollge(flg + FDEC, t - 8);
            f16x8 xa = {};
            if (quad == 0) {
                const float* tp = trg + (size_t)(2 * bp + ab) * 1536 + t * 3;
                xa[0] = (f16)tp[0]; xa[1] = (f16)tp[1]; xa[2] = (f16)tp[2];
                xa[3] = (f16)1.0f;
            }
            f32x4 acc[16];
#pragma unroll
            for (int t2 = 0; t2 < 16; t2++) acc[t2] = MFMA16(xa, XWd[t2], z4);
            float* ow = &xpx[t & 15][qb][c15][0];
#pragma unroll
            for (int q = 0; q < 4; q++) {
                if (quad < 2) {
                    f32x4 w4;
                    w4[0] = qb ? acc[q*4+0][1] : acc[q*4+0][0];
                    w4[1] = qb ? acc[q*4+1][1] : acc[q*4+1][0];
                    w4[2] = qb ? acc[q*4+2][1] : acc[q*4+2][0];
                    w4[3] = qb ? acc[q*4+3][1] : acc[q*4+3][0];
                    *(f32x4*)(ow + q * 4) = w4;
                }
            }
            pub(flg + FXP, t + 1, lane == 0);
        }
    } else if (wv == 1) {
        // ============ encoder L2 input projection (+ dec2 weight staging) ====
        f16x8 Wi0[16], Wi1[16];
        float b2v[16];
#pragma unroll
        for (int t2 = 0; t2 < 16; t2++) {
            const int n = fragN(t2, c15); const float s = fragS(t2);
            Wi0[t2] = ldfrag(e2ih, n, quad * 8, s);
            Wi1[t2] = ldfrag(e2ih, n, 32 + quad * 8, s);
            b2v[t2] = s * e2b[n];
        }
#pragma unroll 1
        for (unsigned tau = 0; tau < 1024; ++tau) {
            if ((tau & 1) == 0) pollge(flg + FL1, (tau + 2 > 1024u) ? 1024u : tau + 2);
            if ((tau & 7) == 0 && tau >= 16) pollge(flg + FL2, tau - 8);
            const f16* hb = &h1r[tau & 15][0][0];
            f16x8 a0 = *(const f16x8*)(hb + ab * 64 + quad * 8);
            f16x8 a1 = *(const f16x8*)(hb + ab * 64 + 32 + quad * 8);
            f32x4 acc[16];
#pragma unroll
            for (int t2 = 0; t2 < 16; t2++)
                acc[t2] = MFMA16(a1, Wi1[t2], MFMA16(a0, Wi0[t2], z4));
            float* ow = &ipr[tau & 15][qb][c15][0];
#pragma unroll
            for (int q = 0; q < 4; q++) {
                if (quad < 2) {
                    f32x4 w4;
                    w4[0] = (qb ? acc[q*4+0][1] : acc[q*4+0][0]) + b2v[q*4+0];
                    w4[1] = (qb ? acc[q*4+1][1] : acc[q*4+1][0]) + b2v[q*4+1];
                    w4[2] = (qb ? acc[q*4+2][1] : acc[q*4+2][0]) + b2v[q*4+2];
                    w4[3] = (qb ? acc[q*4+3][1] : acc[q*4+3][0]) + b2v[q*4+3];
                    *(f32x4*)(ow + q * 4) = w4;
                }
            }
            if (tau < 32) {
                // stage one dec2 merged-weight frag row per tick
                const int fi = (int)tau;
                const int t2s = fi & 15, kh = fi >> 4;
                const int nL = fragN(t2s, c15);
                const int kk = kh * 32 + quad * 8;
                const float ss = fragS(t2s);
                const float* pa  = d2ih + (size_t)nL * 64 + kk;
                const float* pb2 = d2hh + (size_t)nL * 64 + kk;
                f16x8 r;
#pragma unroll
                for (int j = 0; j < 8; j++) r[j] = (f16)(ss * (pa[j] + pb2[j]));
                *(f16x8*)&sfr[fi][lane][0] = r;
            } else if (tau == 32) {
#pragma unroll
                for (int j = 0; j < 4; j++) {
                    const int t2s = quad * 4 + j;
                    db2l[c15][t2s] = fragS(t2s) * d2b[fragN(t2s, c15)];
                }
            }
            pub(flg + FIP, tau + 1, lane == 0);
        }
        pub(flg + FS, 1, lane == 0);
    } else if (wv == 2) {
        // ================= encoder L2 recurrence (critical wave) ============
        f16x8 Wh0[16], Wh1[16];
#pragma unroll
        for (int t2 = 0; t2 < 16; t2++) {
            const int n = fragN(t2, c15); const float s = fragS(t2);
            Wh0[t2] = ldfrag(e2hh, n, quad * 8, s);
            Wh1[t2] = ldfrag(e2hh, n, 32 + quad * 8, s);
        }
        float cs[4] = {0.f, 0.f, 0.f, 0.f};
        pollge(flg + FIP, 5);
        f32x4 xt[4];
        { const float* xp = &ipr[0][qb][c15][0];
#pragma unroll
          for (int q = 0; q < 4; q++) xt[q] = *(const f32x4*)(xp + q * 4); }
        f16x8 b0, b1;
        b0 = *(const f16x8*)(h2b + ab * 64 + quad * 8);
        b1 = *(const f16x8*)(h2b + ab * 64 + 32 + quad * 8);
#pragma unroll 1
        for (unsigned tau = 0; tau < 1024; ++tau) {
            if ((tau & 3) == 0) pollge(flg + FIP, (tau + 5 > 1024u) ? 1024u : tau + 5);
            f32x4 acc[16];
#pragma unroll
            for (int t2 = 0; t2 < 16; t2++)
                acc[t2] = MFMA16(b1, Wh1[t2], MFMA16(b0, Wh0[t2], z4));
#pragma unroll
            for (int q = 0; q < 4; q++) {
                float v0 = (qb ? acc[q*4+0][1] : acc[q*4+0][0]) + xt[q][0];
                float v1 = (qb ? acc[q*4+1][1] : acc[q*4+1][0]) + xt[q][1];
                float v2 = (qb ? acc[q*4+2][1] : acc[q*4+2][0]) + xt[q][2];
                float v3 = (qb ? acc[q*4+3][1] : acc[q*4+3][0]) + xt[q][3];
                float iv = sig2(v0), fv = sig2(v1);
                float gv = fmaf(2.0f, sig2(v2), -1.0f), ov = sig2(v3);
                cs[q] = fv * cs[q] + iv * gv;
                if (quad < 2) h2b[qb * 64 + q * 16 + c15] = (f16)(ov * tanh2(cs[q]));
            }
            pub(flg + FL2, tau + 1, lane == 0);
            b0 = *(const f16x8*)(h2b + ab * 64 + quad * 8);
            b1 = *(const f16x8*)(h2b + ab * 64 + 32 + quad * 8);
            { const float* xp = &ipr[(tau + 1) & 15][qb][c15][0];   // stale-safe at 1023
#pragma unroll
              for (int q = 0; q < 4; q++) xt[q] = *(const f32x4*)(xp + q * 4); }
        }
        // ================= fused decoder dec1 + dec2 ========================
        f16x8 D0[16], D1[16];
#pragma unroll
        for (int t2 = 0; t2 < 16; t2++) {
            const int n = fragN(t2, c15); const float s = fragS(t2);
            D0[t2] = ldfrag(d1hh, n, quad * 8, s);
            D1[t2] = ldfrag(d1hh, n, 32 + quad * 8, s);
        }
        pollge(flg + FS, 1);
        pollge(flg + FXP, 5);
        { const float* xp = &xpx[0][qb][c15][0];
#pragma unroll
          for (int q = 0; q < 4; q++) xt[q] = *(const f32x4*)(xp + q * 4); }
        f16x8 a0 = *(const f16x8*)(h2b + ab * 64 + quad * 8);          // h2(enc final)
        f16x8 a1 = *(const f16x8*)(h2b + ab * 64 + 32 + quad * 8);
        // cs[] carries c2 straight from the encoder -- no handoff needed
#pragma unroll 1
        for (unsigned t = 0; t < 511; ++t) {
            if ((t & 3) == 0) pollge(flg + FXP, (t + 5 > 511u) ? 511u : t + 5);
            // ---- dec1 ----
            f32x4 acc[16];
#pragma unroll
            for (int t2 = 0; t2 < 16; t2++)
                acc[t2] = MFMA16(a1, D1[t2], MFMA16(a0, D0[t2], z4));
            float c1d[4];
#pragma unroll
            for (int q = 0; q < 4; q++) {
                float v0 = (qb ? acc[q*4+0][1] : acc[q*4+0][0]) + xt[q][0];
                float v1 = (qb ? acc[q*4+1][1] : acc[q*4+1][0]) + xt[q][1];
                float v2 = (qb ? acc[q*4+2][1] : acc[q*4+2][0]) + xt[q][2];
                float v3 = (qb ? acc[q*4+3][1] : acc[q*4+3][0]) + xt[q][3];
                float iv = sig2(v0), fv = sig2(v1);
                float gv = fmaf(2.0f, sig2(v2), -1.0f), ov = sig2(v3);
                c1d[q] = fv * cs[q] + iv * gv;
                if (quad < 2) h1d[qb * 64 + q * 16 + c15] = (f16)(ov * tanh2(c1d[q]));
            }
            // dec2 quarter-0 weight frags (double-buffered from LDS)
            f16x8 S0[2][4], S1[2][4];
#pragma unroll
            for (int j = 0; j < 4; j++) {
                S0[0][j] = *(const f16x8*)&sfr[j][lane][0];
                S1[0][j] = *(const f16x8*)&sfr[16 + j][lane][0];
            }
            asm volatile("s_waitcnt lgkmcnt(0)" ::: "memory");   // h1d committed
            f16x8 m0 = *(const f16x8*)(h1d + ab * 64 + quad * 8);
            f16x8 m1 = *(const f16x8*)(h1d + ab * 64 + 32 + quad * 8);
            // ---- dec2 ----
#pragma unroll
            for (int q = 0; q < 4; q++) {
                const int cur = q & 1, nxt = cur ^ 1;
                if (q < 3) {
#pragma unroll
                    for (int j = 0; j < 4; j++) {
                        const int tn = (q + 1) * 4 + j;
                        S0[nxt][j] = *(const f16x8*)&sfr[tn][lane][0];
                        S1[nxt][j] = *(const f16x8*)&sfr[16 + tn][lane][0];
                    }
                }
                f32x4 dbq = *(const f32x4*)&db2l[c15][q * 4];
                f32x4 ac0 = MFMA16(m1, S1[cur][0], MFMA16(m0, S0[cur][0], z4));
                f32x4 ac1 = MFMA16(m1, S1[cur][1], MFMA16(m0, S0[cur][1], z4));
                f32x4 ac2 = MFMA16(m1, S1[cur][2], MFMA16(m0, S0[cur][2], z4));
                f32x4 ac3 = MFMA16(m1, S1[cur][3], MFMA16(m0, S0[cur][3], z4));
                float v0 = (qb ? ac0[1] : ac0[0]) + dbq[0];
                float v1 = (qb ? ac1[1] : ac1[0]) + dbq[1];
                float v2 = (qb ? ac2[1] : ac2[0]) + dbq[2];
                float v3 = (qb ? ac3[1] : ac3[0]) + dbq[3];
                float i2 = sig2(v0), f2 = sig2(v1);
                float g2 = fmaf(2.0f, sig2(v2), -1.0f), o2 = sig2(v3);
                cs[q] = f2 * c1d[q] + i2 * g2;
                if (quad < 2) {
                    f16 hh = (f16)(o2 * tanh2(cs[q]));
                    h2b[qb * 64 + q * 16 + c15] = hh;
                    ringo[qb][t & 31][q * 16 + c15] = hh;
                }
            }
            pub(flg + FDEC, t + 1, lane == 0);
            a0 = *(const f16x8*)(h2b + ab * 64 + quad * 8);
            a1 = *(const f16x8*)(h2b + ab * 64 + 32 + quad * 8);
            { const float* xp = &xpx[(t + 1) & 15][qb][c15][0];     // stale-safe at 510
#pragma unroll
              for (int q = 0; q < 4; q++) xt[q] = *(const f32x4*)(xp + q * 4); }
        }
    } else {
        // ================= enc L1 x-projection producer =====================
        f16x8 XW1[16];
#pragma unroll
        for (int t2 = 0; t2 < 16; t2++) {
            const int n = fragN(t2, c15); const float s = fragS(t2);
            f16x8 r = {};
            if (quad == 0) {
                r[0] = (f16)(s * e1ih[n * 3 + 0]);
                r[1] = (f16)(s * e1ih[n * 3 + 1]);
                r[2] = (f16)(s * e1ih[n * 3 + 2]);
                r[3] = (f16)(s * e1b[n]);
            }
            XW1[t2] = r;
        }
#pragma unroll 1
        for (unsigned tau = 0; tau < 1024; ++tau) {
            if ((tau & 7) == 0 && tau >= 16) pollge(flg + FL1, tau - 8);
            f16x8 xa = {};
            if (quad == 0) {
                const float* sp = src + (size_t)(2 * bp + ab) * 3072 + tau * 3;
                xa[0] = (f16)sp[0]; xa[1] = (f16)sp[1]; xa[2] = (f16)sp[2];
                xa[3] = (f16)1.0f;
            }
            f32x4 acc[16];
#pragma unroll
            for (int t2 = 0; t2 < 16; t2++) acc[t2] = MFMA16(xa, XW1[t2], z4);
            float* ow = &xpx[tau & 15][qb][c15][0];
#pragma unroll
            for (int q = 0; q < 4; q++) {
                if (quad < 2) {
                    f32x4 w4;
                    w4[0] = qb ? acc[q*4+0][1] : acc[q*4+0][0];
                    w4[1] = qb ? acc[q*4+1][1] : acc[q*4+1][0];
                    w4[2] = qb ? acc[q*4+2][1] : acc[q*4+2][0];
                    w4[3] = qb ? acc[q*4+3][1] : acc[q*4+3][0];
                    *(f32x4*)(ow + q * 4) = w4;
                }
            }
            pub(flg + FXP1, tau + 1, lane == 0);
        }
        // ================= FC head ==========================================
        f16x8 FW0 = {}, FW1 = {};
        float fb = 0.f;
        if (c15 < 3) {
#pragma unroll
            for (int j = 0; j < 8; j++) {
                FW0[j] = (f16)fcW[c15 * 64 + quad * 8 + j];
                FW1[j] = (f16)fcW[c15 * 64 + 32 + quad * 8 + j];
            }
            fb = fcb[c15];
        }
#pragma unroll 1
        for (int k = 1; k <= 31; k++) {
            pollge(flg + FDEC, (unsigned)(k * 16));
            const int base = ((k - 1) * 16) & 31;
#pragma unroll
            for (int b = 0; b < 2; b++) {
                const f16* rp = &ringo[b][0][0];
                f16x8 fa0 = *(const f16x8*)(rp + (base + c15) * 72 + quad * 8);
                f16x8 fa1 = *(const f16x8*)(rp + (base + c15) * 72 + 32 + quad * 8);
                f32x4 acc = MFMA16(fa1, FW1, MFMA16(fa0, FW0, z4));
                if (c15 < 3) {
                    float* ob = out + (((size_t)(2 * bp + b) * 512 + (k * 16 - 15)) * 3) + c15;
#pragma unroll
                    for (int rg = 0; rg < 4; rg++)
                        ob[(quad * 4 + rg) * 3] = acc[rg] + fb;
                }
            }
        }
        // drain: steps 496..510 (slots 16..30) -> rows 497..511
        pollge(flg + FDEC, 511);
        {
            const int base = 16;
#pragma unroll
            for (int b = 0; b < 2; b++) {
                const f16* rp = &ringo[b][0][0];
                f16x8 fa0 = *(const f16x8*)(rp + (base + c15) * 72 + quad * 8);
                f16x8 fa1 = *(const f16x8*)(rp + (base + c15) * 72 + 32 + quad * 8);
                f32x4 acc = MFMA16(fa1, FW1, MFMA16(fa0, FW0, z4));
                if (c15 < 3) {
                    float* ob = out + (((size_t)(2 * bp + b) * 512 + 497) * 3) + c15;
#pragma unroll
                    for (int rg = 0; rg < 4; rg++) {
                        int step = quad * 4 + rg;
                        if (step < 15) ob[step * 3] = acc[rg] + fb;
                    }
                }
            }
        }
    }
}

extern "C" void kernel_launch(void* const* d_in, const int* in_sizes, int n_in,
                              void* d_out, int out_size, void* d_ws, size_t ws_size,
                              hipStream_t stream)
{
    const float* src   = (const float*)d_in[0];
    const float* trg   = (const float*)d_in[1];
    const float* e1ih  = (const float*)d_in[2];
    const float* e1hh  = (const float*)d_in[3];
    const float* e1b   = (const float*)d_in[4];
    const float* e2ih  = (const float*)d_in[5];
    const float* e2hh  = (const float*)d_in[6];
    const float* e2b   = (const float*)d_in[7];
    const float* dd1ih = (const float*)d_in[8];
    const float* dd1hh = (const float*)d_in[9];
    const float* dd1b  = (const float*)d_in[10];
    const float* dd2ih = (const float*)d_in[11];
    const float* dd2hh = (const float*)d_in[12];
    const float* dd2b  = (const float*)d_in[13];
    const float* fcW   = (const float*)d_in[14];
    const float* fcb   = (const float*)d_in[15];
    float* out = (float*)d_out;

    static bool attr_set = false;
    if (!attr_set) {
        hipFuncSetAttribute((const void*)seq2seq_kernel,
                            hipFuncAttributeMaxDynamicSharedMemorySize, SMEM_BYTES);
        attr_set = true;
    }

    // outputs[:, 0, :] stays 0; decoder fills t >= 1
    hipMemsetAsync(d_out, 0, (size_t)out_size * sizeof(float), stream);

    seq2seq_kernel<<<256, 256, SMEM_BYTES, stream>>>(src, trg,
                                            e1ih, e1hh, e1b, e2ih, e2hh, e2b,
                                            dd1ih, dd1hh, dd1b, dd2ih, dd2hh, dd2b,
                                            fcW, fcb, out);
}

// Round 6
// 830.560 us; speedup vs baseline: 2.6222x; 2.3664x over previous
//
#include <hip/hip_runtime.h>
#include <math.h>

typedef _Float16 f16;
typedef _Float16 f16x8 __attribute__((ext_vector_type(8)));
typedef float    f32x4 __attribute__((ext_vector_type(4)));

#define MFMA16(A, B, C) __builtin_amdgcn_mfma_f32_16x16x32_f16((A), (B), (C), 0, 0, 0)
#define LOG2E 1.44269504088896f

// Weights/biases pre-scaled by -log2e (sigmoid) or -2*log2e (g gate):
// sigma(z) = rcp(1 + 2^acc) with a bare v_exp_f32.
__device__ __forceinline__ float sig2(float a) {
    return __builtin_amdgcn_rcpf(1.0f + __builtin_amdgcn_exp2f(a));
}
__device__ __forceinline__ float tanh2(float c) {
    return fmaf(2.0f, sig2(c * (-2.0f * LOG2E)), -1.0f);
}

__device__ __forceinline__ f16x8 ldfrag(const float* __restrict__ W, int n, int k0, float s) {
    const float* p = W + (size_t)n * 64 + k0;
    f16x8 r;
#pragma unroll
    for (int j = 0; j < 8; j++) r[j] = (f16)(s * p[j]);
    return r;
}

// One block per BATCH PAIR; 512 threads = 8 waves, layer-specialized:
// waves 0-3 ("A") = encoder L1 / decoder dec1; waves 4-7 ("B") = encoder L2 /
// decoder dec2. FC head: h2 history ring (16 steps) + 2 MFMAs on waves 6-7
// every 16 steps. M=2 MFMA rows: batch = row&1 -> C reg0=batch0, reg1=batch1.
//
// ROUND-6 change vs round-0: encoder L2's input projection E2ih@h1 is
// computed by A-waves (which already hold the h1(tau-1) fragments for their
// own hh-MFMA -- zero extra LDS reads) one tick AHEAD, into a double-buffered
// f32 pre-gate ring prj. B (now computing h2(tau-2) at tick tau) reads one
// f32x4 of pre-gates instead of 8 ih-MFMAs + 2 ds_reads on its post-barrier
// critical chain. Per-SIMD MFMA issue count unchanged; ~8 MFMAs move off the
// serial chain into A's slack.
__global__ __launch_bounds__(512, 1)
void seq2seq_kernel(const float* __restrict__ src, const float* __restrict__ trg,
                    const float* __restrict__ e1ih, const float* __restrict__ e1hh,
                    const float* __restrict__ e1b,
                    const float* __restrict__ e2ih, const float* __restrict__ e2hh,
                    const float* __restrict__ e2b,
                    const float* __restrict__ d1ih, const float* __restrict__ d1hh,
                    const float* __restrict__ d1b,
                    const float* __restrict__ d2ih, const float* __restrict__ d2hh,
                    const float* __restrict__ d2b,
                    const float* __restrict__ fcW, const float* __restrict__ fcb,
                    float* __restrict__ out)
{
    const int bp   = blockIdx.x;
    const int tid  = threadIdx.x;
    const int wv   = tid >> 6;               // 0..7
    const bool isB = (wv >= 4);
    const int wvg  = wv & 3;
    const int lane = tid & 63;
    const int quad = lane >> 4;
    const int c15  = lane & 15;
    const int u16  = wvg * 16 + c15;
    const int qb   = quad & 1;               // batch this lane's activations
    const int ab   = c15 & 1;                // batch this lane's A-row feeds

    __shared__ __align__(16) float xst[1024][8];   // [t][bat*4+c] src, 32 KB
    __shared__ __align__(16) float tst[512][8];    // trg, 16 KB
    __shared__ __align__(16) f16 h1l[2][2][64];    // [buf][bat][u]
    __shared__ __align__(16) f16 h2l[2][2][64];
    __shared__ float c1buf[2][64];                 // dec1 cell out (A -> B)
    __shared__ float c2buf[2][64];                 // dec2 cell out (B -> A)
    __shared__ __align__(16) f16 ring[2][16][72];  // [bat][step&15][u] h2 history
    __shared__ __align__(16) float prj[2][2][64][4]; // L2 ih pre-gates [buf][bat][u][g], 4 KB

    // ---- one-time staging of src/trg into LDS ----
    {
        const float* s0 = src + (size_t)(2 * bp) * 3072;
        const float* s1 = s0 + 3072;
        for (int i = tid; i < 3072; i += 512) {
            int t = i / 3, c = i - 3 * t;
            xst[t][c]     = s0[i];
            xst[t][4 + c] = s1[i];
        }
        const float* t0p = trg + (size_t)(2 * bp) * 1536;
        const float* t1p = t0p + 1536;
        for (int i = tid; i < 1536; i += 512) {
            int t = i / 3, c = i - 3 * t;
            tst[t][c]     = t0p[i];
            tst[t][4 + c] = t1p[i];
        }
    }

    // ---- group-specialized encoder weights ----
    f16x8 E1hh[4][2], E2ih[4][2];            // A: own hh + L2's ih (proj producer)
    f16x8 E2hh[4][2];                        // B: hh only
    float xw[4][3], bias1[4];
    f32x4 bs2[4];                            // B: bias2 splat (MFMA C-init)
    if (!isB) {
#pragma unroll
        for (int g = 0; g < 4; g++) {
            const float s = (g == 2) ? (-2.0f * LOG2E) : (-LOG2E);
            const int n = g * 64 + u16;
#pragma unroll
            for (int c = 0; c < 2; c++) {
                E1hh[g][c] = ldfrag(e1hh, n, c * 32 + quad * 8, s);
                E2ih[g][c] = ldfrag(e2ih, n, c * 32 + quad * 8, s);
            }
            xw[g][0] = s * e1ih[n * 3 + 0];
            xw[g][1] = s * e1ih[n * 3 + 1];
            xw[g][2] = s * e1ih[n * 3 + 2];
            bias1[g] = s * e1b[n];
        }
    } else {
#pragma unroll
        for (int g = 0; g < 4; g++) {
            const float s = (g == 2) ? (-2.0f * LOG2E) : (-LOG2E);
            const int n = g * 64 + u16;
#pragma unroll
            for (int c = 0; c < 2; c++)
                E2hh[g][c] = ldfrag(e2hh, n, c * 32 + quad * 8, s);
            float bv = s * e2b[n];
            bs2[g] = (f32x4){bv, bv, bv, bv};
        }
    }

    float c1 = 0.f, c2 = 0.f;                // c1 lives in A, c2 in B
    if (tid < 256) {
        (&h1l[0][0][0])[tid] = (f16)0.f;
        (&h2l[0][0][0])[tid] = (f16)0.f;
    }
    __syncthreads();

    const f32x4 z4 = {0.f, 0.f, 0.f, 0.f};

    // x prefetch registers (A only)
    f32x4 xq = z4, xnq = z4;
    if (!isB) xq = *(const f32x4*)&xst[0][qb * 4];

    // ---------------- encoder: 1026 pipelined ticks, 1 barrier each --------
    // tick tau: A computes h1(tau) [tau<1024] AND proj(tau-1)=E2ih@h1(tau-1)
    //           [1<=tau<=1024] reusing the same a0/a1 fragments;
    //           B computes h2(tau-2)=f(proj(tau-2), h2(tau-3)) [tau>=2].
#pragma unroll 1
    for (int tau = 0; tau <= 1025; tau++) {
        if (!isB) {
            if (tau <= 1024) {
                const f16* h1p = h1l[(tau + 1) & 1][ab];   // h1(tau-1)
                f16x8 a0 = *(const f16x8*)(h1p + quad * 8);
                f16x8 a1 = *(const f16x8*)(h1p + 32 + quad * 8);
                if (tau < 1024) {            // L1: h1(tau) = f(h1(tau-1), x(tau))
                    float xt[4];
#pragma unroll
                    for (int g = 0; g < 4; g++)
                        xt[g] = fmaf(xw[g][0], xq.x,
                                fmaf(xw[g][1], xq.y, fmaf(xw[g][2], xq.z, bias1[g])));
                    f32x4 acc[4];
#pragma unroll
                    for (int g = 0; g < 4; g++)
                        acc[g] = MFMA16(a1, E1hh[g][1], MFMA16(a0, E1hh[g][0], z4));
                    float v[4];
#pragma unroll
                    for (int g = 0; g < 4; g++)
                        v[g] = (qb ? acc[g][1] : acc[g][0]) + xt[g];
                    float iv = sig2(v[0]), fv = sig2(v[1]);
                    float gv = fmaf(2.0f, sig2(v[2]), -1.0f), ov = sig2(v[3]);
                    c1 = fv * c1 + iv * gv;
                    if (quad < 2) h1l[tau & 1][quad][u16] = (f16)(ov * tanh2(c1));
                    // prefetch next x (read-only region; off the post-barrier burst)
                    const int tn = (tau + 1 < 1024) ? tau + 1 : 1023;
                    xnq = *(const f32x4*)&xst[tn][qb * 4];
                }
                if (tau >= 1) {              // proj(tau-1) = E2ih @ h1(tau-1)
                    f32x4 ap[4];
#pragma unroll
                    for (int g = 0; g < 4; g++)
                        ap[g] = MFMA16(a1, E2ih[g][1], MFMA16(a0, E2ih[g][0], z4));
                    if (quad < 2) {
                        f32x4 pv;
#pragma unroll
                        for (int g = 0; g < 4; g++)
                            pv[g] = qb ? ap[g][1] : ap[g][0];
                        *(f32x4*)&prj[(tau + 1) & 1][qb][u16][0] = pv;
                    }
                }
            }
        } else {
            if (tau >= 2) {                  // L2: h2(tau-2) = f(proj(tau-2), h2(tau-3))
                const f16* h2p = h2l[(tau + 1) & 1][ab];   // h2(tau-3)
                f32x4 pj = *(const f32x4*)&prj[tau & 1][qb][u16][0];  // proj(tau-2)
                f16x8 b0 = *(const f16x8*)(h2p + quad * 8);
                f16x8 b1 = *(const f16x8*)(h2p + 32 + quad * 8);
                f32x4 accB[4];               // bias via C-init
#pragma unroll
                for (int g = 0; g < 4; g++)
                    accB[g] = MFMA16(b1, E2hh[g][1], MFMA16(b0, E2hh[g][0], bs2[g]));
                float v[4];
#pragma unroll
                for (int g = 0; g < 4; g++)
                    v[g] = pj[g] + (qb ? accB[g][1] : accB[g][0]);
                float iv = sig2(v[0]), fv = sig2(v[1]);
                float gv = fmaf(2.0f, sig2(v[2]), -1.0f), ov = sig2(v[3]);
                c2 = fv * c2 + iv * gv;
                if (quad < 2) h2l[tau & 1][quad][u16] = (f16)(ov * tanh2(c2));
            }
        }
        __syncthreads();
        if (!isB) xq = xnq;
    }
    // h2(1023) in h2l[1025&1 = 1]; c2 in B registers

    // ---------------- decoder weights (group-specialized) -------------------
    f16x8 D1hh[4][2];                        // A
    f16x8 W2s[4][2];                         // B
    float dxw[4][3], db1[4];
    f32x4 db2s[4];                           // B: dec2 bias splat (C-init)
    if (!isB) {
#pragma unroll
        for (int g = 0; g < 4; g++) {
            const float s = (g == 2) ? (-2.0f * LOG2E) : (-LOG2E);
            const int n = g * 64 + u16;
#pragma unroll
            for (int c = 0; c < 2; c++)
                D1hh[g][c] = ldfrag(d1hh, n, c * 32 + quad * 8, s);
            dxw[g][0] = s * d1ih[n * 3 + 0];
            dxw[g][1] = s * d1ih[n * 3 + 1];
            dxw[g][2] = s * d1ih[n * 3 + 2];
            db1[g] = s * d1b[n];
        }
    } else {
#pragma unroll
        for (int g = 0; g < 4; g++) {
            const float s = (g == 2) ? (-2.0f * LOG2E) : (-LOG2E);
            const int n = g * 64 + u16;
#pragma unroll
            for (int c = 0; c < 2; c++) {
                const int k0 = c * 32 + quad * 8;
                const float* pa = d2ih + (size_t)n * 64 + k0;
                const float* pb = d2hh + (size_t)n * 64 + k0;
                f16x8 r2;
#pragma unroll
                for (int j = 0; j < 8; j++) r2[j] = (f16)(s * (pa[j] + pb[j]));
                W2s[g][c] = r2;
            }
            float bv = s * d2b[n];
            db2s[g] = (f32x4){bv, bv, bv, bv};
        }
        // seed c2buf with encoder final c2 (A reads it at t=0)
        if (quad < 2) c2buf[quad][u16] = c2;
    }
    // FC: register B-fragments of fcW^T (waves 6-7), B[k][n]=fcW[n][k], n=c15
    f16x8 FW0 = {}, FW1 = {};
    float fb = 0.f;
    if (wv >= 6 && c15 < 3) {
#pragma unroll
        for (int j = 0; j < 8; j++) {
            FW0[j] = (f16)fcW[c15 * 64 + quad * 8 + j];
            FW1[j] = (f16)fcW[c15 * 64 + 32 + quad * 8 + j];
        }
        fb = fcb[c15];
    }
    __syncthreads();

    // trg prefetch registers (A only)
    f32x4 tq = z4, tnq = z4;
    if (!isB) tq = *(const f32x4*)&tst[0][qb * 4];

    // ---------------- decoder: 511 steps, 2 barriers each -------------------
    // (serial chain c2->dec1->c1->dec2 has zero slack; 2 handoffs/step is
    //  structural -- each cell's output feeds the next cell cross-group)
    // NOTE: encoder leaves h2(1023) in h2l[1], so A reads h2l[w] (=(t+1)&1)
    // and B writes h2l[r] (=t&1) -- parity flipped vs round-0.
#pragma unroll 1
    for (int t = 0; t < 511; t++) {
        const int r = t & 1, w = r ^ 1;
        if (!isB) {
            // ---- dec1 (waves 0-3) ----
            const f16* hp = h2l[w][ab];      // h2d(t-1)
            f16x8 a0 = *(const f16x8*)(hp + quad * 8);
            f16x8 a1 = *(const f16x8*)(hp + 32 + quad * 8);
            float cdin = c2buf[qb][u16];
            float xt[4];
#pragma unroll
            for (int g = 0; g < 4; g++)
                xt[g] = fmaf(dxw[g][0], tq.x,
                        fmaf(dxw[g][1], tq.y, fmaf(dxw[g][2], tq.z, db1[g])));
            f32x4 acc[4];
#pragma unroll
            for (int g = 0; g < 4; g++)
                acc[g] = MFMA16(a1, D1hh[g][1], MFMA16(a0, D1hh[g][0], z4));
            float v[4];
#pragma unroll
            for (int g = 0; g < 4; g++)
                v[g] = (qb ? acc[g][1] : acc[g][0]) + xt[g];
            float iv = sig2(v[0]), fv = sig2(v[1]);
            float gv = fmaf(2.0f, sig2(v[2]), -1.0f), ov = sig2(v[3]);
            float c1d = fv * cdin + iv * gv;
            if (quad < 2) {
                h1l[w][quad][u16] = (f16)(ov * tanh2(c1d));
                c1buf[quad][u16]  = c1d;
            }
            const int tn = (t + 1 < 511) ? t + 1 : 510;
            tnq = *(const f32x4*)&tst[tn][qb * 4];
        } else if (wv >= 6 && t > 0 && (t & 15) == 0) {
            // ---- batched FC for steps t-16..t-1 (2 MFMAs), overlapped ----
            const int bsel = wv - 6;
            const f16* rp = &ring[bsel][0][0];
            f16x8 fa0 = *(const f16x8*)(rp + c15 * 72 + quad * 8);
            f16x8 fa1 = *(const f16x8*)(rp + c15 * 72 + 32 + quad * 8);
            f32x4 acc = MFMA16(fa1, FW1, MFMA16(fa0, FW0, z4));
            if (c15 < 3) {
                float* ob = out + (((size_t)(2 * bp + bsel) * 512 + (t - 15)) * 3) + c15;
#pragma unroll
                for (int rg = 0; rg < 4; rg++)
                    ob[(quad * 4 + rg) * 3] = acc[rg] + fb;
            }
        }
        __syncthreads();   // B1: h1d, c1d visible
        if (!isB) tq = tnq;

        if (isB) {
            // ---- dec2 (waves 4-7): x = h = h1d ----
            const f16* np = h1l[w][ab];
            f16x8 m0 = *(const f16x8*)(np + quad * 8);
            f16x8 m1 = *(const f16x8*)(np + 32 + quad * 8);
            float c1in = c1buf[qb][u16];
            f32x4 acc[4];
#pragma unroll
            for (int g = 0; g < 4; g++)
                acc[g] = MFMA16(m1, W2s[g][1], MFMA16(m0, W2s[g][0], db2s[g]));
            float v[4];
#pragma unroll
            for (int g = 0; g < 4; g++)
                v[g] = (qb ? acc[g][1] : acc[g][0]);
            float i2 = sig2(v[0]), f2 = sig2(v[1]);
            float g2 = fmaf(2.0f, sig2(v[2]), -1.0f), o2 = sig2(v[3]);
            float c2d = f2 * c1in + i2 * g2;
            if (quad < 2) {
                f16 hh = (f16)(o2 * tanh2(c2d));
                h2l[r][quad][u16] = hh;      // parity-flipped (see note above)
                c2buf[quad][u16]  = c2d;
                ring[quad][t & 15][u16] = hh;   // FC history
            }
        }
        __syncthreads();   // B2: hD(t), c2d visible
    }

    // drain: FC for steps 496..510 (ring slots 0..14) -> out rows 497..511
    if (wv >= 6) {
        const int bsel = wv - 6;
        const f16* rp = &ring[bsel][0][0];
        f16x8 fa0 = *(const f16x8*)(rp + c15 * 72 + quad * 8);
        f16x8 fa1 = *(const f16x8*)(rp + c15 * 72 + 32 + quad * 8);
        f32x4 acc = MFMA16(fa1, FW1, MFMA16(fa0, FW0, z4));
        if (c15 < 3) {
            float* ob = out + (((size_t)(2 * bp + bsel) * 512 + 497) * 3) + c15;
#pragma unroll
            for (int rg = 0; rg < 4; rg++) {
                int step = quad * 4 + rg;
                if (step < 15) ob[step * 3] = acc[rg] + fb;
            }
        }
    }
}

extern "C" void kernel_launch(void* const* d_in, const int* in_sizes, int n_in,
                              void* d_out, int out_size, void* d_ws, size_t ws_size,
                              hipStream_t stream)
{
    const float* src   = (const float*)d_in[0];
    const float* trg   = (const float*)d_in[1];
    const float* e1ih  = (const float*)d_in[2];
    const float* e1hh  = (const float*)d_in[3];
    const float* e1b   = (const float*)d_in[4];
    const float* e2ih  = (const float*)d_in[5];
    const float* e2hh  = (const float*)d_in[6];
    const float* e2b   = (const float*)d_in[7];
    const float* dd1ih = (const float*)d_in[8];
    const float* dd1hh = (const float*)d_in[9];
    const float* dd1b  = (const float*)d_in[10];
    const float* dd2ih = (const float*)d_in[11];
    const float* dd2hh = (const float*)d_in[12];
    const float* dd2b  = (const float*)d_in[13];
    const float* fcW   = (const float*)d_in[14];
    const float* fcb   = (const float*)d_in[15];
    float* out = (float*)d_out;

    // outputs[:, 0, :] stays 0; decoder fills t >= 1
    hipMemsetAsync(d_out, 0, (size_t)out_size * sizeof(float), stream);

    seq2seq_kernel<<<256, 512, 0, stream>>>(src, trg,
                                            e1ih, e1hh, e1b, e2ih, e2hh, e2b,
                                            dd1ih, dd1hh, dd1b, dd2ih, dd2hh, dd2b,
                                            fcW, fcb, out);
}